// Round 1
// baseline (3900.933 us; speedup 1.0000x reference)
//
#include <hip/hip_runtime.h>
#include <math.h>

#define NN 50000
#define MM 800000
#define HH 64

__device__ __forceinline__ float silu_f(float v) {
    return v * (1.0f / (1.0f + __expf(-v)));
}

// ---------------- embedding: h = h_in @ emb_W + emb_b ----------------
__global__ __launch_bounds__(256) void embed_kernel(
    const float* __restrict__ h_in, const float* __restrict__ W,
    const float* __restrict__ b, float* __restrict__ h_out)
{
    const int idx = blockIdx.x * 256 + threadIdx.x;   // over N*64
    const int n = idx >> 6, j = idx & 63;
    float acc = b[j];
    #pragma unroll
    for (int k = 0; k < 16; ++k)
        acc += h_in[n * 16 + k] * W[k * HH + j];
    h_out[idx] = acc;
}

// ---------------- edge kernel: one wave per edge ----------------
__global__ __launch_bounds__(256) void edge_kernel(
    const float* __restrict__ x, const float* __restrict__ h,
    const int* __restrict__ row, const int* __restrict__ col,
    const float* __restrict__ efea,
    const float* __restrict__ W1, const float* __restrict__ b1,
    const float* __restrict__ W2, const float* __restrict__ b2,
    const float* __restrict__ cW1, const float* __restrict__ cb1,
    const float* __restrict__ cW2, const float* __restrict__ cb2,
    float* __restrict__ sum_f, float* __restrict__ cnt,
    float* __restrict__ tmsg)
{
    __shared__ float sbuf[4][140];   // per-wave s vector (137, padded)
    __shared__ float hbuf[4][64];    // per-wave intermediate
    const int wave = threadIdx.x >> 6;
    const int lane = threadIdx.x & 63;
    const int e = blockIdx.x * 4 + wave;          // grid sized exactly M/4
    const int r = row[e];
    const int c = col[e];

    const float rx = x[3*r+0] - x[3*c+0];
    const float ry = x[3*r+1] - x[3*c+1];
    const float rz = x[3*r+2] - x[3*c+2];
    const float r2 = rx*rx + ry*ry + rz*rz;

    float* s = sbuf[wave];
    if (lane == 0) s[0] = r2;
    s[1 + lane]  = h[(size_t)r * HH + lane];
    s[65 + lane] = h[(size_t)c * HH + lane];
    if (lane < 8) s[129 + lane] = efea[(size_t)e * 8 + lane];
    __syncthreads();

    // layer 1: 137 -> 64, SiLU
    float a0 = 0.f, a1 = 0.f, a2 = 0.f, a3 = 0.f;
    #pragma unroll 8
    for (int k = 0; k < 136; k += 4) {
        const float4 sv = *(const float4*)(s + k);
        a0 += sv.x * W1[(k+0)*HH + lane];
        a1 += sv.y * W1[(k+1)*HH + lane];
        a2 += sv.z * W1[(k+2)*HH + lane];
        a3 += sv.w * W1[(k+3)*HH + lane];
    }
    a0 += s[136] * W1[136*HH + lane];
    const float h1 = silu_f((a0+a1) + (a2+a3) + b1[lane]);
    hbuf[wave][lane] = h1;
    __syncthreads();

    // layer 2: 64 -> 64, SiLU  => msg
    const float* hb = hbuf[wave];
    float m0 = 0.f, m1 = 0.f, m2 = 0.f, m3 = 0.f;
    #pragma unroll 8
    for (int k = 0; k < 64; k += 4) {
        const float4 hv = *(const float4*)(hb + k);
        m0 += hv.x * W2[(k+0)*HH + lane];
        m1 += hv.y * W2[(k+1)*HH + lane];
        m2 += hv.z * W2[(k+2)*HH + lane];
        m3 += hv.w * W2[(k+3)*HH + lane];
    }
    const float msg = silu_f((m0+m1) + (m2+m3) + b2[lane]);
    __syncthreads();
    hbuf[wave][lane] = msg;
    __syncthreads();

    // coord layer 1: 64 -> 64, SiLU
    float q0 = 0.f, q1 = 0.f, q2 = 0.f, q3 = 0.f;
    #pragma unroll 8
    for (int k = 0; k < 64; k += 4) {
        const float4 hv = *(const float4*)(hb + k);
        q0 += hv.x * cW1[(k+0)*HH + lane];
        q1 += hv.y * cW1[(k+1)*HH + lane];
        q2 += hv.z * cW1[(k+2)*HH + lane];
        q3 += hv.w * cW1[(k+3)*HH + lane];
    }
    const float c1 = silu_f((q0+q1) + (q2+q3) + cb1[lane]);

    // coord layer 2: 64 -> 1 (no act): wave reduction
    float t = c1 * cW2[lane];
    #pragma unroll
    for (int off = 32; off > 0; off >>= 1)
        t += __shfl_xor(t, off, 64);
    const float cm = t + cb2[0];

    // scatter
    atomicAdd(&tmsg[(size_t)r * HH + lane], msg);
    if (lane < 3) {
        const float comp = (lane == 0) ? rx : ((lane == 1) ? ry : rz);
        atomicAdd(&sum_f[3*r + lane], comp * cm);
    } else if (lane == 3) {
        atomicAdd(&cnt[r], 1.0f);
    }
}

// ---------------- node kernel: one wave per node ----------------
__global__ __launch_bounds__(256) void node_kernel(
    float* __restrict__ x, float* __restrict__ h,
    const float* __restrict__ sum_f, const float* __restrict__ cnt,
    const float* __restrict__ tmsg,
    const float* __restrict__ W1, const float* __restrict__ nb1,
    const float* __restrict__ W2, const float* __restrict__ nb2)
{
    __shared__ float inb[4][128];
    __shared__ float mid[4][64];
    const int wave = threadIdx.x >> 6;
    const int lane = threadIdx.x & 63;
    const int n = blockIdx.x * 4 + wave;          // grid sized exactly N/4

    inb[wave][lane]      = h[(size_t)n * HH + lane];
    inb[wave][64 + lane] = tmsg[(size_t)n * HH + lane];
    if (lane < 3) {
        const float cn = fmaxf(cnt[n], 1.0f);
        float tf = sum_f[3*n + lane] / cn;
        tf = fminf(fmaxf(tf, -100.0f), 100.0f);
        x[3*n + lane] += tf;
    }
    __syncthreads();

    const float* in = inb[wave];
    float a0 = 0.f, a1 = 0.f, a2 = 0.f, a3 = 0.f;
    #pragma unroll 8
    for (int k = 0; k < 128; k += 4) {
        const float4 v = *(const float4*)(in + k);
        a0 += v.x * W1[(k+0)*HH + lane];
        a1 += v.y * W1[(k+1)*HH + lane];
        a2 += v.z * W1[(k+2)*HH + lane];
        a3 += v.w * W1[(k+3)*HH + lane];
    }
    const float m = silu_f((a0+a1) + (a2+a3) + nb1[lane]);
    mid[wave][lane] = m;
    __syncthreads();

    const float* md = mid[wave];
    float c0 = 0.f, c1 = 0.f, c2 = 0.f, c3 = 0.f;
    #pragma unroll 8
    for (int k = 0; k < 64; k += 4) {
        const float4 v = *(const float4*)(md + k);
        c0 += v.x * W2[(k+0)*HH + lane];
        c1 += v.y * W2[(k+1)*HH + lane];
        c2 += v.z * W2[(k+2)*HH + lane];
        c3 += v.w * W2[(k+3)*HH + lane];
    }
    h[(size_t)n * HH + lane] = (c0+c1) + (c2+c3) + nb2[lane];
}

extern "C" void kernel_launch(void* const* d_in, const int* in_sizes, int n_in,
                              void* d_out, int out_size, void* d_ws, size_t ws_size,
                              hipStream_t stream) {
    const float* x_in  = (const float*)d_in[0];
    const float* h_in  = (const float*)d_in[1];
    const int*   row   = (const int*)d_in[2];
    const int*   col   = (const int*)d_in[3];
    const float* efea  = (const float*)d_in[4];
    const float* emb_W = (const float*)d_in[5];
    const float* emb_b = (const float*)d_in[6];
    const float* eW1   = (const float*)d_in[7];   // [2,137,64]
    const float* eb1   = (const float*)d_in[8];   // [2,64]
    const float* eW2   = (const float*)d_in[9];   // [2,64,64]
    const float* eb2   = (const float*)d_in[10];  // [2,64]
    const float* cW1   = (const float*)d_in[11];  // [2,64,64]
    const float* cb1   = (const float*)d_in[12];  // [2,64]
    const float* cW2   = (const float*)d_in[13];  // [2,64,1]
    const float* cb2   = (const float*)d_in[14];  // [2,1]
    const float* nW1   = (const float*)d_in[15];  // [2,128,64]
    const float* nb1   = (const float*)d_in[16];  // [2,64]
    const float* nW2   = (const float*)d_in[17];  // [2,64,64]
    const float* nb2   = (const float*)d_in[18];  // [2,64]

    float* out = (float*)d_out;
    float* x = out;               // N*3
    float* h = out + NN * 3;      // N*64

    float* ws      = (float*)d_ws;
    float* sum_f   = ws;               // N*3
    float* cnt     = ws + NN * 3;      // N
    float* tot_msg = ws + NN * 4;      // N*64

    hipMemcpyAsync(x, x_in, (size_t)NN * 3 * sizeof(float),
                   hipMemcpyDeviceToDevice, stream);
    embed_kernel<<<(NN * HH) / 256, 256, 0, stream>>>(h_in, emb_W, emb_b, h);

    for (int i = 0; i < 2; ++i) {
        hipMemsetAsync(ws, 0, (size_t)NN * 68 * sizeof(float), stream);
        edge_kernel<<<MM / 4, 256, 0, stream>>>(
            x, h, row, col, efea,
            eW1 + (size_t)i * 137 * 64, eb1 + i * 64,
            eW2 + (size_t)i * 64 * 64,  eb2 + i * 64,
            cW1 + (size_t)i * 64 * 64,  cb1 + i * 64,
            cW2 + (size_t)i * 64,       cb2 + i,
            sum_f, cnt, tot_msg);
        node_kernel<<<NN / 4, 256, 0, stream>>>(
            x, h, sum_f, cnt, tot_msg,
            nW1 + (size_t)i * 128 * 64, nb1 + i * 64,
            nW2 + (size_t)i * 64 * 64,  nb2 + i * 64);
    }
}

// Round 2
// 825.673 us; speedup vs baseline: 4.7245x; 4.7245x over previous
//
#include <hip/hip_runtime.h>
#include <math.h>

#define NN 50000
#define MM 800000
#define HH 64
#define NB_EDGE 512
#define NTILE 12500                 // MM / 64 edges per block-tile
#define WOFF_BYTES 13600000         // 3.4M floats of aggregation buffers

typedef short bf16x8 __attribute__((ext_vector_type(8)));
typedef float f32x4  __attribute__((ext_vector_type(4)));

__device__ __forceinline__ float silu_f(float v) {
    return v * (1.0f / (1.0f + __expf(-v)));
}
// round-to-nearest-even fp32 -> bf16 bits
__device__ __forceinline__ unsigned short bfb(float a) {
    unsigned u = __float_as_uint(a);
    return (unsigned short)((u + 0x7FFF + ((u >> 16) & 1)) >> 16);
}
__device__ __forceinline__ unsigned pk2(float a, float b) {
    return (unsigned)bfb(a) | ((unsigned)bfb(b) << 16);
}

// ---------------- weight pre-swizzle into MFMA B-fragment layout (bf16) ----
// W1B: [5 ksteps][4 nt][64 lane][8 j]   (K padded 137->160, r2 row moved to k'=136)
// W2B/cW1B: [2][4][64][8]
__global__ __launch_bounds__(256) void prep_kernel(
    const float* __restrict__ eW1, const float* __restrict__ eW2,
    const float* __restrict__ cW1, unsigned short* __restrict__ wsW)
{
    const int i = blockIdx.x * 256 + threadIdx.x;     // 0 .. 36863
    const int layer = i / 18432;
    const int rem = i - layer * 18432;
    float val;
    if (rem < 10240) {
        const int j = rem & 7, lane = (rem >> 3) & 63, nt = (rem >> 9) & 3, s = rem >> 11;
        const int kp = s * 32 + ((lane >> 4) << 3) + j;
        const int n  = nt * 16 + (lane & 15);
        if (kp > 136) val = 0.0f;
        else {
            const int k = (kp == 136) ? 0 : kp + 1;   // k'=136 is the r2 row (orig k=0)
            val = eW1[layer * 137 * 64 + k * 64 + n];
        }
    } else if (rem < 14336) {
        const int r2 = rem - 10240;
        const int j = r2 & 7, lane = (r2 >> 3) & 63, nt = (r2 >> 9) & 3, s = r2 >> 11;
        val = eW2[layer * 4096 + (s * 32 + ((lane >> 4) << 3) + j) * 64 + nt * 16 + (lane & 15)];
    } else {
        const int r3 = rem - 14336;
        const int j = r3 & 7, lane = (r3 >> 3) & 63, nt = (r3 >> 9) & 3, s = r3 >> 11;
        val = cW1[layer * 4096 + (s * 32 + ((lane >> 4) << 3) + j) * 64 + nt * 16 + (lane & 15)];
    }
    wsW[i] = bfb(val);
}

// ---------------- embedding ----------------
__global__ __launch_bounds__(256) void embed_kernel(
    const float* __restrict__ h_in, const float* __restrict__ W,
    const float* __restrict__ b, float* __restrict__ h_out)
{
    const int idx = blockIdx.x * 256 + threadIdx.x;
    const int n = idx >> 6, j = idx & 63;
    float acc = b[j];
    #pragma unroll
    for (int k = 0; k < 16; ++k)
        acc += h_in[n * 16 + k] * W[k * HH + j];
    h_out[idx] = acc;
}

// ---------------- MFMA edge kernel: 16 edges per wave ----------------
__global__ __launch_bounds__(256, 2) void edge_mfma_kernel(
    const float* __restrict__ x, const float* __restrict__ h,
    const int* __restrict__ row, const int* __restrict__ col,
    const float* __restrict__ efea,
    const unsigned short* __restrict__ w1b, const unsigned short* __restrict__ w2b,
    const unsigned short* __restrict__ cw1b,
    const float* __restrict__ b1, const float* __restrict__ b2,
    const float* __restrict__ cb1, const float* __restrict__ cw2,
    const float* __restrict__ cb2,
    float* __restrict__ sum_f, float* __restrict__ cnt, float* __restrict__ tmsg)
{
    // per-wave LDS regions (no cross-wave sharing)
    __shared__ __align__(16) unsigned short S[4][16][168];   // s-vector, K-major, padded
    __shared__ __align__(16) unsigned short H1[4][16][72];   // hidden1 bf16
    __shared__ __align__(16) unsigned short MS[4][16][72];   // msg bf16
    __shared__ float RV[4][16][3];
    __shared__ int   RI[4][16];

    const int tid = threadIdx.x;
    const int w = tid >> 6, lane = tid & 63;
    const int l15 = lane & 15, quad = lane >> 4;
    const int le = lane >> 2, sub = lane & 3;

    // persistent W1 B-fragments (reused across all tiles of this block)
    bf16x8 w1f[5][4];
    #pragma unroll
    for (int s = 0; s < 5; ++s)
        #pragma unroll
        for (int nt = 0; nt < 4; ++nt)
            w1f[s][nt] = *(const bf16x8*)(w1b + ((s * 4 + nt) * 64 + lane) * 8);

    float b1v[4], b2v[4], cb1v[4], cw2v[4];
    #pragma unroll
    for (int nt = 0; nt < 4; ++nt) {
        b1v[nt]  = b1[nt * 16 + l15];
        b2v[nt]  = b2[nt * 16 + l15];
        cb1v[nt] = cb1[nt * 16 + l15];
        cw2v[nt] = cw2[nt * 16 + l15];
    }
    const float cb2s = cb2[0];

    for (int bt = blockIdx.x; bt < NTILE; bt += NB_EDGE) {
        const int t = bt * 4 + w;            // wave-group id < 50000
        const int e = t * 16 + le;
        const int r = row[e], c = col[e];

        // ---- gather stage: 4 lanes per edge ----
        unsigned short* Srow = &S[w][le][0];
        {
            const float4* hr = (const float4*)(h + (size_t)r * HH + sub * 16);
            float4 a0 = hr[0], a1 = hr[1], a2 = hr[2], a3 = hr[3];
            uint4 u0 = { pk2(a0.x, a0.y), pk2(a0.z, a0.w), pk2(a1.x, a1.y), pk2(a1.z, a1.w) };
            uint4 u1 = { pk2(a2.x, a2.y), pk2(a2.z, a2.w), pk2(a3.x, a3.y), pk2(a3.z, a3.w) };
            *(uint4*)&Srow[sub * 16]     = u0;
            *(uint4*)&Srow[sub * 16 + 8] = u1;
            const float4* hc = (const float4*)(h + (size_t)c * HH + sub * 16);
            float4 c0 = hc[0], c1 = hc[1], c2 = hc[2], c3 = hc[3];
            uint4 v0 = { pk2(c0.x, c0.y), pk2(c0.z, c0.w), pk2(c1.x, c1.y), pk2(c1.z, c1.w) };
            uint4 v1 = { pk2(c2.x, c2.y), pk2(c2.z, c2.w), pk2(c3.x, c3.y), pk2(c3.z, c3.w) };
            *(uint4*)&Srow[64 + sub * 16]     = v0;
            *(uint4*)&Srow[64 + sub * 16 + 8] = v1;
        }
        if (sub == 0) {
            const float rx = x[3 * r + 0] - x[3 * c + 0];
            const float ry = x[3 * r + 1] - x[3 * c + 1];
            const float rz = x[3 * r + 2] - x[3 * c + 2];
            const float r2 = rx * rx + ry * ry + rz * rz;
            RV[w][le][0] = rx; RV[w][le][1] = ry; RV[w][le][2] = rz;
            RI[w][le] = r;
            *(unsigned*)&Srow[136] = (unsigned)bfb(r2);   // element 137 zeroed too
        } else if (sub == 1) {
            const float4* ef = (const float4*)(efea + (size_t)e * 8);
            float4 e0 = ef[0], e1 = ef[1];
            uint4 ue = { pk2(e0.x, e0.y), pk2(e0.z, e0.w), pk2(e1.x, e1.y), pk2(e1.z, e1.w) };
            *(uint4*)&Srow[128] = ue;
        } else if (sub == 2) {
            #pragma unroll
            for (int q = 138; q < 154; q += 2) *(unsigned*)&Srow[q] = 0u;
        } else {
            #pragma unroll
            for (int q = 154; q < 168; q += 2) *(unsigned*)&Srow[q] = 0u;
        }
        __syncthreads();

        // ---- GEMM1: S[16x160] @ W1[160x64] ----
        bf16x8 af[5];
        #pragma unroll
        for (int s = 0; s < 5; ++s)
            af[s] = *(const bf16x8*)&S[w][l15][s * 32 + quad * 8];
        #pragma unroll
        for (int nt = 0; nt < 4; ++nt) {
            f32x4 a = {0.f, 0.f, 0.f, 0.f};
            #pragma unroll
            for (int s = 0; s < 5; ++s)
                a = __builtin_amdgcn_mfma_f32_16x16x32_bf16(af[s], w1f[s][nt], a, 0, 0, 0);
            #pragma unroll
            for (int rr = 0; rr < 4; ++rr)
                H1[w][quad * 4 + rr][nt * 16 + l15] = bfb(silu_f(a[rr] + b1v[nt]));
        }
        __syncthreads();

        // ---- GEMM2: H1 @ W2 -> msg; scatter tmsg ----
        bf16x8 a2[2];
        #pragma unroll
        for (int s = 0; s < 2; ++s)
            a2[s] = *(const bf16x8*)&H1[w][l15][s * 32 + quad * 8];
        #pragma unroll
        for (int nt = 0; nt < 4; ++nt) {
            f32x4 m = {0.f, 0.f, 0.f, 0.f};
            #pragma unroll
            for (int s = 0; s < 2; ++s) {
                bf16x8 bf = *(const bf16x8*)(w2b + ((s * 4 + nt) * 64 + lane) * 8);
                m = __builtin_amdgcn_mfma_f32_16x16x32_bf16(a2[s], bf, m, 0, 0, 0);
            }
            #pragma unroll
            for (int rr = 0; rr < 4; ++rr) {
                const float v = silu_f(m[rr] + b2v[nt]);
                MS[w][quad * 4 + rr][nt * 16 + l15] = bfb(v);
                atomicAdd(&tmsg[(size_t)RI[w][quad * 4 + rr] * HH + nt * 16 + l15], v);
            }
        }
        __syncthreads();

        // ---- GEMM3: msg @ cW1 -> c1; dot cW2 -> cm; scatter f ----
        bf16x8 a3[2];
        #pragma unroll
        for (int s = 0; s < 2; ++s)
            a3[s] = *(const bf16x8*)&MS[w][l15][s * 32 + quad * 8];
        float pr[4] = {0.f, 0.f, 0.f, 0.f};
        #pragma unroll
        for (int nt = 0; nt < 4; ++nt) {
            f32x4 q = {0.f, 0.f, 0.f, 0.f};
            #pragma unroll
            for (int s = 0; s < 2; ++s) {
                bf16x8 bf = *(const bf16x8*)(cw1b + ((s * 4 + nt) * 64 + lane) * 8);
                q = __builtin_amdgcn_mfma_f32_16x16x32_bf16(a3[s], bf, q, 0, 0, 0);
            }
            #pragma unroll
            for (int rr = 0; rr < 4; ++rr)
                pr[rr] += silu_f(q[rr] + cb1v[nt]) * cw2v[nt];
        }
        #pragma unroll
        for (int rr = 0; rr < 4; ++rr) {
            float tt = pr[rr];
            tt += __shfl_xor(tt, 1, 64);
            tt += __shfl_xor(tt, 2, 64);
            tt += __shfl_xor(tt, 4, 64);
            tt += __shfl_xor(tt, 8, 64);
            const float cm = tt + cb2s;
            const int g = quad * 4 + rr;
            if (l15 < 3)       atomicAdd(&sum_f[3 * RI[w][g] + l15], RV[w][g][l15] * cm);
            else if (l15 == 3) atomicAdd(&cnt[RI[w][g]], 1.0f);
        }
    }
}

// ---------------- node kernel: one wave per node (fp32) ----------------
__global__ __launch_bounds__(256) void node_kernel(
    float* __restrict__ x, float* __restrict__ h,
    const float* __restrict__ sum_f, const float* __restrict__ cnt,
    const float* __restrict__ tmsg,
    const float* __restrict__ W1, const float* __restrict__ nb1,
    const float* __restrict__ W2, const float* __restrict__ nb2)
{
    __shared__ float inb[4][128];
    __shared__ float mid[4][64];
    const int wave = threadIdx.x >> 6;
    const int lane = threadIdx.x & 63;
    const int n = blockIdx.x * 4 + wave;

    inb[wave][lane]      = h[(size_t)n * HH + lane];
    inb[wave][64 + lane] = tmsg[(size_t)n * HH + lane];
    if (lane < 3) {
        const float cn = fmaxf(cnt[n], 1.0f);
        float tf = sum_f[3 * n + lane] / cn;
        tf = fminf(fmaxf(tf, -100.0f), 100.0f);
        x[3 * n + lane] += tf;
    }
    __syncthreads();

    const float* in = inb[wave];
    float a0 = 0.f, a1 = 0.f, a2 = 0.f, a3 = 0.f;
    #pragma unroll 8
    for (int k = 0; k < 128; k += 4) {
        const float4 v = *(const float4*)(in + k);
        a0 += v.x * W1[(k + 0) * HH + lane];
        a1 += v.y * W1[(k + 1) * HH + lane];
        a2 += v.z * W1[(k + 2) * HH + lane];
        a3 += v.w * W1[(k + 3) * HH + lane];
    }
    const float m = silu_f((a0 + a1) + (a2 + a3) + nb1[lane]);
    mid[wave][lane] = m;
    __syncthreads();

    const float* md = mid[wave];
    float c0 = 0.f, c1 = 0.f, c2 = 0.f, c3 = 0.f;
    #pragma unroll 8
    for (int k = 0; k < 64; k += 4) {
        const float4 v = *(const float4*)(md + k);
        c0 += v.x * W2[(k + 0) * HH + lane];
        c1 += v.y * W2[(k + 1) * HH + lane];
        c2 += v.z * W2[(k + 2) * HH + lane];
        c3 += v.w * W2[(k + 3) * HH + lane];
    }
    h[(size_t)n * HH + lane] = (c0 + c1) + (c2 + c3) + nb2[lane];
}

extern "C" void kernel_launch(void* const* d_in, const int* in_sizes, int n_in,
                              void* d_out, int out_size, void* d_ws, size_t ws_size,
                              hipStream_t stream) {
    const float* x_in  = (const float*)d_in[0];
    const float* h_in  = (const float*)d_in[1];
    const int*   row   = (const int*)d_in[2];
    const int*   col   = (const int*)d_in[3];
    const float* efea  = (const float*)d_in[4];
    const float* emb_W = (const float*)d_in[5];
    const float* emb_b = (const float*)d_in[6];
    const float* eW1   = (const float*)d_in[7];
    const float* eb1   = (const float*)d_in[8];
    const float* eW2   = (const float*)d_in[9];
    const float* eb2   = (const float*)d_in[10];
    const float* cW1   = (const float*)d_in[11];
    const float* cb1   = (const float*)d_in[12];
    const float* cW2   = (const float*)d_in[13];
    const float* cb2   = (const float*)d_in[14];
    const float* nW1   = (const float*)d_in[15];
    const float* nb1   = (const float*)d_in[16];
    const float* nW2   = (const float*)d_in[17];
    const float* nb2   = (const float*)d_in[18];

    float* out = (float*)d_out;
    float* xo = out;                 // N*3
    float* ho = out + NN * 3;        // N*64

    float* ws    = (float*)d_ws;
    float* sum_f = ws;               // N*3
    float* cnt   = ws + NN * 3;      // N
    float* tmsg  = ws + NN * 4;      // N*64
    unsigned short* wsW = (unsigned short*)((char*)d_ws + WOFF_BYTES);

    hipMemcpyAsync(xo, x_in, (size_t)NN * 3 * sizeof(float),
                   hipMemcpyDeviceToDevice, stream);
    prep_kernel<<<144, 256, 0, stream>>>(eW1, eW2, cW1, wsW);
    embed_kernel<<<(NN * HH) / 256, 256, 0, stream>>>(h_in, emb_W, emb_b, ho);

    for (int i = 0; i < 2; ++i) {
        hipMemsetAsync(ws, 0, (size_t)NN * 68 * sizeof(float), stream);
        edge_mfma_kernel<<<NB_EDGE, 256, 0, stream>>>(
            xo, ho, row, col, efea,
            wsW + i * 18432, wsW + i * 18432 + 10240, wsW + i * 18432 + 14336,
            eb1 + i * 64, eb2 + i * 64, cb1 + i * 64, cW2 + i * 64, cb2 + i,
            sum_f, cnt, tmsg);
        node_kernel<<<NN / 4, 256, 0, stream>>>(
            xo, ho, sum_f, cnt, tmsg,
            nW1 + (size_t)i * 128 * 64, nb1 + i * 64,
            nW2 + (size_t)i * 64 * 64,  nb2 + i * 64);
    }
}